// Round 4
// baseline (1540.937 us; speedup 1.0000x reference)
//
#include <hip/hip_runtime.h>
#include <cfloat>
#include <cmath>

#define N_TOK 65536
#define N_E   2048
#define E_DIM 256
#define BETA  0.25

// ws layout (bytes)
#define WS_LOSSPART 0          // double[2048]  -> 16384
#define WS_A        16384      // float[65536]  -> 278528
#define WS_B        278528     // float[2048]   -> 286720
#define WS_IDXF     286720     // int[65536]    -> 548864
#define WS_COUNTS   548864     // int[2048]     -> 557056

#define ZS_STRIDE 68           // 64 + 4 pad, keeps 16B alignment per row

// ---------------------------------------------------------------------------
// numpy f32 pairwise sum of squares of a 256-row, AVX512_SKX model (verified
// bit-exact in round 3).
// ---------------------------------------------------------------------------
__device__ __forceinline__ float np_sq_pairwise256(const float* __restrict__ x) {
  float blk[2];
#pragma unroll
  for (int h = 0; h < 2; ++h) {
    const float* p = x + h * 128;
    float lane[16];
#pragma unroll
    for (int l = 0; l < 16; ++l) {
      const float q0 = __fmul_rn(p[l +   0], p[l +   0]);
      const float q1 = __fmul_rn(p[l +  16], p[l +  16]);
      const float q2 = __fmul_rn(p[l +  32], p[l +  32]);
      const float q3 = __fmul_rn(p[l +  48], p[l +  48]);
      const float q4 = __fmul_rn(p[l +  64], p[l +  64]);
      const float q5 = __fmul_rn(p[l +  80], p[l +  80]);
      const float q6 = __fmul_rn(p[l +  96], p[l +  96]);
      const float q7 = __fmul_rn(p[l + 112], p[l + 112]);
      lane[l] = __fadd_rn(__fadd_rn(__fadd_rn(q0, q1), __fadd_rn(q2, q3)),
                          __fadd_rn(__fadd_rn(q4, q5), __fadd_rn(q6, q7)));
    }
    float u[8];
#pragma unroll
    for (int l = 0; l < 8; ++l) u[l] = __fadd_rn(lane[l], lane[l + 8]);
    float v[4];
#pragma unroll
    for (int l = 0; l < 4; ++l) v[l] = __fadd_rn(u[l], u[l + 4]);
    const float w0 = __fadd_rn(v[0], v[2]);
    const float w1 = __fadd_rn(v[1], v[3]);
    blk[h] = __fadd_rn(w0, w1);
  }
  return __fadd_rn(blk[0], blk[1]);
}

__global__ __launch_bounds__(256) void k_ab(const float* __restrict__ z,
                                            const float* __restrict__ E,
                                            float* __restrict__ a,
                                            float* __restrict__ b) {
  const int r = blockIdx.x * 256 + threadIdx.x;
  if (r < N_TOK) {
    a[r] = np_sq_pairwise256(z + (size_t)r * E_DIM);
  } else {
    const int e = r - N_TOK;
    if (e < N_E) b[e] = np_sq_pairwise256(E + (size_t)e * E_DIM);
  }
}

__global__ void k_zero(int* __restrict__ counts) {
  const int i = blockIdx.x * 256 + threadIdx.x;
  if (i < N_E) counts[i] = 0;
}

// transpose E[2048][256] -> Et[256][2048] (bit copy; coalesced writes)
__global__ __launch_bounds__(256) void k_tr(const float* __restrict__ E,
                                            float* __restrict__ Et) {
  const int id = blockIdx.x * 256 + threadIdx.x;   // 524288 total
  const int k = id >> 11;
  const int j = id & 2047;
  Et[id] = E[(size_t)j * E_DIM + k];
}

// ---------------------------------------------------------------------------
// main pass v2: 8x8 register tile per thread, B-operand (Et) streamed from
// L2, z-tile LDS-resident (padded stride 68). Per (t,j): m = sequential
// fused-FMA chain k=0..255 (bit-identical to round 3), D = fl(fl(a+b)-2m),
// lexicographic (D, idx) argmin.
// ---------------------------------------------------------------------------
__global__ __launch_bounds__(256, 2) void k_main(
    const float* __restrict__ z, const float* __restrict__ Et,
    const float* __restrict__ a, const float* __restrict__ b,
    int* __restrict__ idxF, float* __restrict__ out_idx) {
  extern __shared__ float zs[];   // [E_DIM][ZS_STRIDE]

  const int tid = threadIdx.x;
  const int tx = tid & 31;   // code group: 8 codes
  const int ty = tid >> 5;   // token group: 8 tokens
  const size_t tok0 = (size_t)blockIdx.x * 64;

  // stage z transposed: zs[k][t] (exact bit copies)
  {
    const int t = tid >> 2;          // 0..63
    const int kq = (tid & 3) * 4;    // 0,4,8,12
    const float* zp = z + (tok0 + t) * E_DIM;
    for (int rep = 0; rep < E_DIM; rep += 16) {
      const int k = rep + kq;
      const float4 v = *(const float4*)(zp + k);
      zs[(k + 0) * ZS_STRIDE + t] = v.x;
      zs[(k + 1) * ZS_STRIDE + t] = v.y;
      zs[(k + 2) * ZS_STRIDE + t] = v.z;
      zs[(k + 3) * ZS_STRIDE + t] = v.w;
    }
  }
  __syncthreads();

  float av[8];
#pragma unroll
  for (int i = 0; i < 8; ++i) av[i] = a[tok0 + ty * 8 + i];

  float v1[8];
  int j1[8];
#pragma unroll
  for (int i = 0; i < 8; ++i) { v1[i] = FLT_MAX; j1[i] = 0; }

  for (int ct = 0; ct < N_E / 256; ++ct) {
    float acc[8][8];
#pragma unroll
    for (int i = 0; i < 8; ++i)
#pragma unroll
      for (int j = 0; j < 8; ++j) acc[i][j] = 0.f;

    const float* ep = Et + ct * 256 + tx * 8;
    const float* zrow = zs + ty * 8;
#pragma unroll 4
    for (int k = 0; k < E_DIM; ++k) {
      const float4 za0 = *(const float4*)(zrow + k * ZS_STRIDE);
      const float4 za1 = *(const float4*)(zrow + k * ZS_STRIDE + 4);
      const float4 eb0 = *(const float4*)(ep + k * 2048);
      const float4 eb1 = *(const float4*)(ep + k * 2048 + 4);
      const float zv[8] = {za0.x, za0.y, za0.z, za0.w,
                           za1.x, za1.y, za1.z, za1.w};
      const float ev[8] = {eb0.x, eb0.y, eb0.z, eb0.w,
                           eb1.x, eb1.y, eb1.z, eb1.w};
#pragma unroll
      for (int i = 0; i < 8; ++i)
#pragma unroll
        for (int j = 0; j < 8; ++j)
          acc[i][j] = __fmaf_rn(zv[i], ev[j], acc[i][j]);
    }

    // epilogue: D = fl(fl(a+b) - 2*m), lexicographic top-1 (indices ascend)
    const float4 b40 = *(const float4*)&b[ct * 256 + tx * 8];
    const float4 b41 = *(const float4*)&b[ct * 256 + tx * 8 + 4];
    const float bv[8] = {b40.x, b40.y, b40.z, b40.w,
                         b41.x, b41.y, b41.z, b41.w};
    const int cbase = ct * 256 + tx * 8;
#pragma unroll
    for (int i = 0; i < 8; ++i)
#pragma unroll
      for (int j = 0; j < 8; ++j) {
        const float X = __fadd_rn(av[i], bv[j]);
        const float D = __fsub_rn(X, __fmul_rn(2.0f, acc[i][j]));
        const int c = cbase + j;
        if (D < v1[i] || (D == v1[i] && c < j1[i])) { v1[i] = D; j1[i] = c; }
      }
    __syncthreads();   // re-converge waves for Et L1 temporal locality
  }

  // lexicographic (value, index) butterfly min across the 32 tx lanes
#pragma unroll
  for (int m = 1; m < 32; m <<= 1) {
#pragma unroll
    for (int i = 0; i < 8; ++i) {
      const float ov = __shfl_xor(v1[i], m, 64);
      const int   oj = __shfl_xor(j1[i], m, 64);
      if (ov < v1[i] || (ov == v1[i] && oj < j1[i])) { v1[i] = ov; j1[i] = oj; }
    }
  }
  if (tx == 0) {
#pragma unroll
    for (int i = 0; i < 8; ++i) {
      const int t = (int)tok0 + ty * 8 + i;
      idxF[t] = j1[i];
      out_idx[t] = (float)j1[i];
    }
  }
}

// gather z_q, write z_q_st = fl(z + fl(zq - z)), accumulate f64 loss partials
__global__ __launch_bounds__(256) void k_gather(
    const float* __restrict__ z, const float* __restrict__ E,
    const int* __restrict__ idxF, float* __restrict__ out0,
    double* __restrict__ lossPart) {
  double ls = 0.0;
  const int NU = N_TOK * (E_DIM / 4);  // float4 units
  for (int u = blockIdx.x * 256 + threadIdx.x; u < NU; u += 2048 * 256) {
    const int tok = u >> 6;
    const int d4 = (u & 63) * 4;
    const int c = idxF[tok];
    const float4 zq = *(const float4*)&E[(size_t)c * E_DIM + d4];
    const float4 zv = *(const float4*)&z[(size_t)tok * E_DIM + d4];
    float4 o;
    o.x = __fadd_rn(zv.x, __fsub_rn(zq.x, zv.x));
    o.y = __fadd_rn(zv.y, __fsub_rn(zq.y, zv.y));
    o.z = __fadd_rn(zv.z, __fsub_rn(zq.z, zv.z));
    o.w = __fadd_rn(zv.w, __fsub_rn(zq.w, zv.w));
    *(float4*)&out0[(size_t)u * 4] = o;
    double dx;
    dx = (double)zq.x - (double)zv.x; ls += dx * dx;
    dx = (double)zq.y - (double)zv.y; ls += dx * dx;
    dx = (double)zq.z - (double)zv.z; ls += dx * dx;
    dx = (double)zq.w - (double)zv.w; ls += dx * dx;
  }
  __shared__ double red[256];
  red[threadIdx.x] = ls;
  __syncthreads();
  for (int s = 128; s; s >>= 1) {
    if (threadIdx.x < s) red[threadIdx.x] += red[threadIdx.x + s];
    __syncthreads();
  }
  if (threadIdx.x == 0) lossPart[blockIdx.x] = red[0];
}

__global__ __launch_bounds__(256) void k_hist(const int* __restrict__ idxF,
                                              int* __restrict__ counts) {
  const int t = blockIdx.x * 256 + threadIdx.x;
  atomicAdd(&counts[idxF[t]], 1);
}

__global__ __launch_bounds__(256) void k_final(
    const double* __restrict__ lossPart, const int* __restrict__ counts,
    float* __restrict__ outLoss, float* __restrict__ outPerp) {
  __shared__ double rs[256], rh[256];
  double s = 0.0, h = 0.0;
  for (int j = threadIdx.x; j < 2048; j += 256) s += lossPart[j];
  for (int j = threadIdx.x; j < N_E; j += 256) {
    const double p = (double)counts[j] * (1.0 / (double)N_TOK);
    h -= p * log(p + 1e-10);
  }
  rs[threadIdx.x] = s;
  rh[threadIdx.x] = h;
  __syncthreads();
  for (int m = 128; m; m >>= 1) {
    if (threadIdx.x < m) {
      rs[threadIdx.x] += rs[threadIdx.x + m];
      rh[threadIdx.x] += rh[threadIdx.x + m];
    }
    __syncthreads();
  }
  if (threadIdx.x == 0) {
    outLoss[0] = (float)((1.0 + BETA) * rs[0] / (double)((size_t)N_TOK * E_DIM));
    outPerp[0] = (float)exp(rh[0]);
  }
}

extern "C" void kernel_launch(void* const* d_in, const int* in_sizes, int n_in,
                              void* d_out, int out_size, void* d_ws, size_t ws_size,
                              hipStream_t stream) {
  const float* z = (const float*)d_in[0];
  const float* E = (const float*)d_in[1];

  float* out0 = (float*)d_out;                       // z_q_st [65536*256]
  float* outLoss = out0 + (size_t)N_TOK * E_DIM;     // scalar
  float* outPerp = outLoss + 1;                      // scalar
  float* outIdx = outPerp + 1;                       // idx as float [65536]

  char* ws = (char*)d_ws;
  double* lossPart = (double*)(ws + WS_LOSSPART);
  float* a = (float*)(ws + WS_A);
  float* b = (float*)(ws + WS_B);
  int* idxF = (int*)(ws + WS_IDXF);
  int* counts = (int*)(ws + WS_COUNTS);

  // Et (2 MB) lives in the z_q_st output region as scratch: k_main reads it,
  // then k_gather fully overwrites the region. Deterministic per call.
  float* Et = out0;

  (void)hipFuncSetAttribute(reinterpret_cast<const void*>(k_main),
                            hipFuncAttributeMaxDynamicSharedMemorySize,
                            E_DIM * ZS_STRIDE * 4);

  hipLaunchKernelGGL(k_zero, dim3(8), dim3(256), 0, stream, counts);
  hipLaunchKernelGGL(k_ab, dim3((N_TOK + N_E) / 256), dim3(256), 0, stream,
                     z, E, a, b);
  hipLaunchKernelGGL(k_tr, dim3((N_E * E_DIM) / 256), dim3(256), 0, stream,
                     E, Et);
  hipLaunchKernelGGL(k_main, dim3(N_TOK / 64), dim3(256),
                     E_DIM * ZS_STRIDE * 4, stream,
                     z, Et, a, b, idxF, outIdx);
  hipLaunchKernelGGL(k_gather, dim3(2048), dim3(256), 0, stream,
                     z, E, idxF, out0, lossPart);
  hipLaunchKernelGGL(k_hist, dim3(N_TOK / 256), dim3(256), 0, stream, idxF, counts);
  hipLaunchKernelGGL(k_final, dim3(1), dim3(256), 0, stream,
                     lossPart, counts, outLoss, outPerp);
}

// Round 5
// 897.310 us; speedup vs baseline: 1.7173x; 1.7173x over previous
//
#include <hip/hip_runtime.h>
#include <cfloat>
#include <cmath>

#define N_TOK 65536
#define N_E   2048
#define E_DIM 256
#define BETA  0.25

#define TN 256          // codes per tile
#define KC 16           // k per staged chunk
#define NCHUNK (E_DIM / KC)
#define ES_CH 12        // floats per 8-code chunk (8 data + 4 pad)
#define ES_W  388       // floats per k-row (32*12=384, pad to 388: 16B-aligned, 128B-offset rows)
#define ZS_W  68        // 64 tokens + 4 pad

// ws layout (bytes)
#define WS_LOSSPART 0          // double[2048]  -> 16384
#define WS_A        16384      // float[65536]  -> 278528
#define WS_B        278528     // float[2048]   -> 286720
#define WS_IDXF     286720     // int[65536]    -> 548864
#define WS_COUNTS   548864     // int[2048]     -> 557056

// ---------------------------------------------------------------------------
// numpy f32 pairwise sum of squares of a 256-row, AVX512_SKX model (verified
// bit-exact in round 3).
// ---------------------------------------------------------------------------
__device__ __forceinline__ float np_sq_pairwise256(const float* __restrict__ x) {
  float blk[2];
#pragma unroll
  for (int h = 0; h < 2; ++h) {
    const float* p = x + h * 128;
    float lane[16];
#pragma unroll
    for (int l = 0; l < 16; ++l) {
      const float q0 = __fmul_rn(p[l +   0], p[l +   0]);
      const float q1 = __fmul_rn(p[l +  16], p[l +  16]);
      const float q2 = __fmul_rn(p[l +  32], p[l +  32]);
      const float q3 = __fmul_rn(p[l +  48], p[l +  48]);
      const float q4 = __fmul_rn(p[l +  64], p[l +  64]);
      const float q5 = __fmul_rn(p[l +  80], p[l +  80]);
      const float q6 = __fmul_rn(p[l +  96], p[l +  96]);
      const float q7 = __fmul_rn(p[l + 112], p[l + 112]);
      lane[l] = __fadd_rn(__fadd_rn(__fadd_rn(q0, q1), __fadd_rn(q2, q3)),
                          __fadd_rn(__fadd_rn(q4, q5), __fadd_rn(q6, q7)));
    }
    float u[8];
#pragma unroll
    for (int l = 0; l < 8; ++l) u[l] = __fadd_rn(lane[l], lane[l + 8]);
    float v[4];
#pragma unroll
    for (int l = 0; l < 4; ++l) v[l] = __fadd_rn(u[l], u[l + 4]);
    const float w0 = __fadd_rn(v[0], v[2]);
    const float w1 = __fadd_rn(v[1], v[3]);
    blk[h] = __fadd_rn(w0, w1);
  }
  return __fadd_rn(blk[0], blk[1]);
}

__global__ __launch_bounds__(256) void k_ab(const float* __restrict__ z,
                                            const float* __restrict__ E,
                                            float* __restrict__ a,
                                            float* __restrict__ b) {
  const int r = blockIdx.x * 256 + threadIdx.x;
  if (r < N_TOK) {
    a[r] = np_sq_pairwise256(z + (size_t)r * E_DIM);
  } else {
    const int e = r - N_TOK;
    if (e < N_E) b[e] = np_sq_pairwise256(E + (size_t)e * E_DIM);
  }
}

__global__ void k_zero(int* __restrict__ counts) {
  const int i = blockIdx.x * 256 + threadIdx.x;
  if (i < N_E) counts[i] = 0;
}

// ---------------------------------------------------------------------------
// main pass v3: double-buffered LDS GEMM. 64 tokens x 256 codes per block,
// 8x8 register tile per thread. Inner loop reads ONLY LDS; next chunk's
// global loads issue before the compute phase (latency hidden), ds_writes
// after, one barrier per chunk. FMA chain per (t,j): single accumulator,
// k ascending 0..255, __fmaf_rn — bit-identical to round 3.
// ---------------------------------------------------------------------------
__global__ __launch_bounds__(256, 2) void k_main(
    const float* __restrict__ z, const float* __restrict__ E,
    const float* __restrict__ a, const float* __restrict__ b,
    int* __restrict__ idxF, float* __restrict__ out_idx) {
  __shared__ __align__(16) float es[2][KC][ES_W];
  __shared__ __align__(16) float zs[2][KC][ZS_W];

  const int tid = threadIdx.x;
  const int tx = tid & 31;   // code group: 8 codes
  const int ty = tid >> 5;   // token group: 8 tokens
  const size_t tok0 = (size_t)blockIdx.x * 64;

  // staging roles
  const int sp  = tid & 3;        // 16B piece within a 64B k-slice
  const int scl = tid >> 2;       // base code (es) / token (zs)

  float av[8];
#pragma unroll
  for (int i = 0; i < 8; ++i) av[i] = a[tok0 + ty * 8 + i];

  float v1[8];
  int j1[8];
#pragma unroll
  for (int i = 0; i < 8; ++i) { v1[i] = FLT_MAX; j1[i] = 0; }

  for (int ct = 0; ct < N_E / TN; ++ct) {
    // hoist epilogue b-loads so latency hides under compute
    const float4 b40 = *(const float4*)&b[ct * TN + tx * 8];
    const float4 b41 = *(const float4*)&b[ct * TN + tx * 8 + 4];

    float acc[8][8];
#pragma unroll
    for (int i = 0; i < 8; ++i)
#pragma unroll
      for (int j = 0; j < 8; ++j) acc[i][j] = 0.f;

    // ---- prologue: stage chunk 0 into buffer 0 ----
    {
      float4 Le0, Le1, Le2, Le3, Lz;
      {
        const size_t ebase = (size_t)(ct * TN) * E_DIM;
        Le0 = *(const float4*)&E[ebase + (size_t)(scl +   0) * E_DIM + sp * 4];
        Le1 = *(const float4*)&E[ebase + (size_t)(scl +  64) * E_DIM + sp * 4];
        Le2 = *(const float4*)&E[ebase + (size_t)(scl + 128) * E_DIM + sp * 4];
        Le3 = *(const float4*)&E[ebase + (size_t)(scl + 192) * E_DIM + sp * 4];
        Lz  = *(const float4*)&z[(tok0 + scl) * E_DIM + sp * 4];
      }
      const int p4 = sp * 4;
      const int s0 = ((scl +   0) >> 3) * ES_CH + (scl & 7);
      const int s1 = ((scl +  64) >> 3) * ES_CH + (scl & 7);
      const int s2 = ((scl + 128) >> 3) * ES_CH + (scl & 7);
      const int s3 = ((scl + 192) >> 3) * ES_CH + (scl & 7);
      es[0][p4 + 0][s0] = Le0.x; es[0][p4 + 1][s0] = Le0.y;
      es[0][p4 + 2][s0] = Le0.z; es[0][p4 + 3][s0] = Le0.w;
      es[0][p4 + 0][s1] = Le1.x; es[0][p4 + 1][s1] = Le1.y;
      es[0][p4 + 2][s1] = Le1.z; es[0][p4 + 3][s1] = Le1.w;
      es[0][p4 + 0][s2] = Le2.x; es[0][p4 + 1][s2] = Le2.y;
      es[0][p4 + 2][s2] = Le2.z; es[0][p4 + 3][s2] = Le2.w;
      es[0][p4 + 0][s3] = Le3.x; es[0][p4 + 1][s3] = Le3.y;
      es[0][p4 + 2][s3] = Le3.z; es[0][p4 + 3][s3] = Le3.w;
      zs[0][p4 + 0][scl] = Lz.x; zs[0][p4 + 1][scl] = Lz.y;
      zs[0][p4 + 2][scl] = Lz.z; zs[0][p4 + 3][scl] = Lz.w;
    }
    __syncthreads();

    // ---- main chunk loop ----
#pragma unroll 2
    for (int kc = 0; kc < NCHUNK; ++kc) {
      const int cur = kc & 1;
      const int nxt = cur ^ 1;

      // issue next chunk's global loads NOW (uniform condition, no divergence)
      float4 Le0, Le1, Le2, Le3, Lz;
      if (kc + 1 < NCHUNK) {
        const int ko = (kc + 1) * KC + sp * 4;
        const size_t ebase = (size_t)(ct * TN) * E_DIM;
        Le0 = *(const float4*)&E[ebase + (size_t)(scl +   0) * E_DIM + ko];
        Le1 = *(const float4*)&E[ebase + (size_t)(scl +  64) * E_DIM + ko];
        Le2 = *(const float4*)&E[ebase + (size_t)(scl + 128) * E_DIM + ko];
        Le3 = *(const float4*)&E[ebase + (size_t)(scl + 192) * E_DIM + ko];
        Lz  = *(const float4*)&z[(tok0 + scl) * E_DIM + ko];
      }

      // compute this chunk from LDS only
#pragma unroll 4
      for (int k = 0; k < KC; ++k) {
        const float4 za0 = *(const float4*)&zs[cur][k][ty * 8];
        const float4 za1 = *(const float4*)&zs[cur][k][ty * 8 + 4];
        const float4 eb0 = *(const float4*)&es[cur][k][tx * ES_CH];
        const float4 eb1 = *(const float4*)&es[cur][k][tx * ES_CH + 4];
        const float zv[8] = {za0.x, za0.y, za0.z, za0.w,
                             za1.x, za1.y, za1.z, za1.w};
        const float ev[8] = {eb0.x, eb0.y, eb0.z, eb0.w,
                             eb1.x, eb1.y, eb1.z, eb1.w};
#pragma unroll
        for (int i = 0; i < 8; ++i)
#pragma unroll
          for (int j = 0; j < 8; ++j)
            acc[i][j] = __fmaf_rn(zv[i], ev[j], acc[i][j]);
      }

      // write staged regs into the other buffer
      if (kc + 1 < NCHUNK) {
        const int p4 = sp * 4;
        const int s0 = ((scl +   0) >> 3) * ES_CH + (scl & 7);
        const int s1 = ((scl +  64) >> 3) * ES_CH + (scl & 7);
        const int s2 = ((scl + 128) >> 3) * ES_CH + (scl & 7);
        const int s3 = ((scl + 192) >> 3) * ES_CH + (scl & 7);
        es[nxt][p4 + 0][s0] = Le0.x; es[nxt][p4 + 1][s0] = Le0.y;
        es[nxt][p4 + 2][s0] = Le0.z; es[nxt][p4 + 3][s0] = Le0.w;
        es[nxt][p4 + 0][s1] = Le1.x; es[nxt][p4 + 1][s1] = Le1.y;
        es[nxt][p4 + 2][s1] = Le1.z; es[nxt][p4 + 3][s1] = Le1.w;
        es[nxt][p4 + 0][s2] = Le2.x; es[nxt][p4 + 1][s2] = Le2.y;
        es[nxt][p4 + 2][s2] = Le2.z; es[nxt][p4 + 3][s2] = Le2.w;
        es[nxt][p4 + 0][s3] = Le3.x; es[nxt][p4 + 1][s3] = Le3.y;
        es[nxt][p4 + 2][s3] = Le3.z; es[nxt][p4 + 3][s3] = Le3.w;
        zs[nxt][p4 + 0][scl] = Lz.x; zs[nxt][p4 + 1][scl] = Lz.y;
        zs[nxt][p4 + 2][scl] = Lz.z; zs[nxt][p4 + 3][scl] = Lz.w;
      }
      __syncthreads();
    }

    // epilogue: D = fl(fl(a+b) - 2*m), lexicographic top-1 (indices ascend)
    const float bv[8] = {b40.x, b40.y, b40.z, b40.w,
                         b41.x, b41.y, b41.z, b41.w};
    const int cbase = ct * TN + tx * 8;
#pragma unroll
    for (int i = 0; i < 8; ++i)
#pragma unroll
      for (int j = 0; j < 8; ++j) {
        const float X = __fadd_rn(av[i], bv[j]);
        const float D = __fsub_rn(X, __fmul_rn(2.0f, acc[i][j]));
        const int c = cbase + j;
        if (D < v1[i] || (D == v1[i] && c < j1[i])) { v1[i] = D; j1[i] = c; }
      }
  }

  // lexicographic (value, index) butterfly min across the 32 tx lanes
#pragma unroll
  for (int m = 1; m < 32; m <<= 1) {
#pragma unroll
    for (int i = 0; i < 8; ++i) {
      const float ov = __shfl_xor(v1[i], m, 64);
      const int   oj = __shfl_xor(j1[i], m, 64);
      if (ov < v1[i] || (ov == v1[i] && oj < j1[i])) { v1[i] = ov; j1[i] = oj; }
    }
  }
  if (tx == 0) {
#pragma unroll
    for (int i = 0; i < 8; ++i) {
      const int t = (int)tok0 + ty * 8 + i;
      idxF[t] = j1[i];
      out_idx[t] = (float)j1[i];
    }
  }
}

// gather z_q, write z_q_st = fl(z + fl(zq - z)), accumulate f64 loss partials
__global__ __launch_bounds__(256) void k_gather(
    const float* __restrict__ z, const float* __restrict__ E,
    const int* __restrict__ idxF, float* __restrict__ out0,
    double* __restrict__ lossPart) {
  double ls = 0.0;
  const int NU = N_TOK * (E_DIM / 4);  // float4 units
  for (int u = blockIdx.x * 256 + threadIdx.x; u < NU; u += 2048 * 256) {
    const int tok = u >> 6;
    const int d4 = (u & 63) * 4;
    const int c = idxF[tok];
    const float4 zq = *(const float4*)&E[(size_t)c * E_DIM + d4];
    const float4 zv = *(const float4*)&z[(size_t)tok * E_DIM + d4];
    float4 o;
    o.x = __fadd_rn(zv.x, __fsub_rn(zq.x, zv.x));
    o.y = __fadd_rn(zv.y, __fsub_rn(zq.y, zv.y));
    o.z = __fadd_rn(zv.z, __fsub_rn(zq.z, zv.z));
    o.w = __fadd_rn(zv.w, __fsub_rn(zq.w, zv.w));
    *(float4*)&out0[(size_t)u * 4] = o;
    double dx;
    dx = (double)zq.x - (double)zv.x; ls += dx * dx;
    dx = (double)zq.y - (double)zv.y; ls += dx * dx;
    dx = (double)zq.z - (double)zv.z; ls += dx * dx;
    dx = (double)zq.w - (double)zv.w; ls += dx * dx;
  }
  __shared__ double red[256];
  red[threadIdx.x] = ls;
  __syncthreads();
  for (int s = 128; s; s >>= 1) {
    if (threadIdx.x < s) red[threadIdx.x] += red[threadIdx.x + s];
    __syncthreads();
  }
  if (threadIdx.x == 0) lossPart[blockIdx.x] = red[0];
}

__global__ __launch_bounds__(256) void k_hist(const int* __restrict__ idxF,
                                              int* __restrict__ counts) {
  const int t = blockIdx.x * 256 + threadIdx.x;
  atomicAdd(&counts[idxF[t]], 1);
}

__global__ __launch_bounds__(256) void k_final(
    const double* __restrict__ lossPart, const int* __restrict__ counts,
    float* __restrict__ outLoss, float* __restrict__ outPerp) {
  __shared__ double rs[256], rh[256];
  double s = 0.0, h = 0.0;
  for (int j = threadIdx.x; j < 2048; j += 256) s += lossPart[j];
  for (int j = threadIdx.x; j < N_E; j += 256) {
    const double p = (double)counts[j] * (1.0 / (double)N_TOK);
    h -= p * log(p + 1e-10);
  }
  rs[threadIdx.x] = s;
  rh[threadIdx.x] = h;
  __syncthreads();
  for (int m = 128; m; m >>= 1) {
    if (threadIdx.x < m) {
      rs[threadIdx.x] += rs[threadIdx.x + m];
      rh[threadIdx.x] += rh[threadIdx.x + m];
    }
    __syncthreads();
  }
  if (threadIdx.x == 0) {
    outLoss[0] = (float)((1.0 + BETA) * rs[0] / (double)((size_t)N_TOK * E_DIM));
    outPerp[0] = (float)exp(rh[0]);
  }
}

extern "C" void kernel_launch(void* const* d_in, const int* in_sizes, int n_in,
                              void* d_out, int out_size, void* d_ws, size_t ws_size,
                              hipStream_t stream) {
  const float* z = (const float*)d_in[0];
  const float* E = (const float*)d_in[1];

  float* out0 = (float*)d_out;                       // z_q_st [65536*256]
  float* outLoss = out0 + (size_t)N_TOK * E_DIM;     // scalar
  float* outPerp = outLoss + 1;                      // scalar
  float* outIdx = outPerp + 1;                       // idx as float [65536]

  char* ws = (char*)d_ws;
  double* lossPart = (double*)(ws + WS_LOSSPART);
  float* a = (float*)(ws + WS_A);
  float* b = (float*)(ws + WS_B);
  int* idxF = (int*)(ws + WS_IDXF);
  int* counts = (int*)(ws + WS_COUNTS);

  hipLaunchKernelGGL(k_zero, dim3(8), dim3(256), 0, stream, counts);
  hipLaunchKernelGGL(k_ab, dim3((N_TOK + N_E) / 256), dim3(256), 0, stream,
                     z, E, a, b);
  hipLaunchKernelGGL(k_main, dim3(N_TOK / 64), dim3(256), 0, stream,
                     z, E, a, b, idxF, outIdx);
  hipLaunchKernelGGL(k_gather, dim3(2048), dim3(256), 0, stream,
                     z, E, idxF, out0, lossPart);
  hipLaunchKernelGGL(k_hist, dim3(N_TOK / 256), dim3(256), 0, stream, idxF, counts);
  hipLaunchKernelGGL(k_final, dim3(1), dim3(256), 0, stream,
                     lossPart, counts, outLoss, outPerp);
}